// Round 3
// baseline (1038.103 us; speedup 1.0000x reference)
//
#include <hip/hip_runtime.h>
#include <hip/hip_bf16.h>
#include <math.h>

// ContextAttention: B=128, S=2048, D=512, H=512
// hidden = W_ctx @ (sum_s score_s * contexts[b,s,:]) + b_ctx  (sum score = 1)

#define B_N 128
#define S_N 2048
#define D_N 512
#define H_N 512

typedef __attribute__((ext_vector_type(8))) short bf16x8;
typedef __attribute__((ext_vector_type(4))) float f32x4;

__device__ __forceinline__ unsigned pk2bf(float x, float y) {
  union { __hip_bfloat162 h; unsigned u; } cv;
  cv.h = __float22bfloat162_rn(make_float2(x, y));   // v_cvt_pk_bf16_f32
  return cv.u;
}

__device__ __forceinline__ float tanh_fast(float x) {
  float ax = fabsf(x);
  float e = __expf(2.0f * ax);
  float t = 1.0f - 2.0f / (e + 1.0f);
  return copysignf(t, x);
}

// ---------------- K-1: detect mask dtype (int32 0/1 vs 1-byte bool) -----------
__global__ void detect_mask_kernel(const unsigned int* __restrict__ mask,
                                   int* __restrict__ flag) {
  int tid = threadIdx.x;
  unsigned int bad = 0;
  for (int i = tid; i < 256; i += 64) bad |= (mask[i] > 1u) ? 1u : 0u;
  unsigned long long b = __ballot(bad != 0);
  if (tid == 0) *flag = (b == 0ull) ? 1 : 0;
}

// ---------------- K0a: pack W_ctx -> bf16, chunked per-BK32-tile LDS image ----
// tile t: 32 KB; byte = (h>>4)*1024 + (k>>3)*256 + (h&15)*16 + (k&7)*2
__global__ __launch_bounds__(256) void packw_kernel(const float* __restrict__ Wc,
                                                    unsigned short* __restrict__ wpack) {
  int idx = blockIdx.x * 256 + threadIdx.x;   // h*64 + t*4 + c
  int h = idx >> 6;
  int t = (idx >> 2) & 15;
  int c = idx & 3;
  const float* src = Wc + (size_t)h * D_N + t * 32 + c * 8;
  float4 v0 = *(const float4*)(src);
  float4 v1 = *(const float4*)(src + 4);
  uint4 o;
  o.x = pk2bf(v0.x, v0.y); o.y = pk2bf(v0.z, v0.w);
  o.z = pk2bf(v1.x, v1.y); o.w = pk2bf(v1.z, v1.w);
  int byte = t * 32768 + (h >> 4) * 1024 + c * 256 + (h & 15) * 16;
  *(uint4*)((char*)wpack + byte) = o;
}

// ---------------- K0b: transpose W_in and W_ctx (fp32) for coalesced dots -----
__global__ __launch_bounds__(256) void transpose_kernel(const float* __restrict__ Win,
    const float* __restrict__ Wc, float* __restrict__ WinT, float* __restrict__ WcT) {
  __shared__ float tile[64][65];
  int bid = blockIdx.x;                  // 0..127
  int m = bid >> 6, tl = bid & 63;
  int tr = (tl >> 3) * 64, tc = (tl & 7) * 64;
  const float* in = m ? Wc : Win;
  float* out = m ? WcT : WinT;
  int tx = threadIdx.x & 63, ty = threadIdx.x >> 6;   // ty 0..3
  #pragma unroll
  for (int i = 0; i < 64; i += 4)
    tile[i + ty][tx] = in[(size_t)(tr + i + ty) * D_N + tc + tx];
  __syncthreads();
  #pragma unroll
  for (int i = 0; i < 64; i += 4)
    out[(size_t)(tc + i + ty) * H_N + tr + tx] = tile[tx][i + ty];
}

// ---------------- K1: qpb[b,h] = inputs[b]·W_in[h] + b_in[h] + b_ctx[h] -------
// WinT layout [D][H]; thread owns 4 consecutive h -> float4 coalesced reads.
__global__ __launch_bounds__(256) void qproj_kernel(const float* __restrict__ inp,
    const float* __restrict__ WinT, const float* __restrict__ bin,
    const float* __restrict__ bctx, float* __restrict__ qpb) {
  int b = blockIdx.x, tid = threadIdx.x;
  __shared__ float xin[D_N];
  __shared__ float4 red[128];
  xin[tid] = inp[b * D_N + tid];
  xin[tid + 256] = inp[b * D_N + tid + 256];
  __syncthreads();
  int hq = tid & 127;          // h = hq*4..hq*4+3
  int dp = tid >> 7;           // d parity (wave-uniform)
  const float4* wt = (const float4*)WinT;
  float4 a = make_float4(0.f, 0.f, 0.f, 0.f);
  #pragma unroll 8
  for (int d = dp; d < D_N; d += 2) {
    float xs = xin[d];
    float4 w = wt[d * 128 + hq];
    a.x += xs * w.x; a.y += xs * w.y; a.z += xs * w.z; a.w += xs * w.w;
  }
  if (dp == 1) red[hq] = a;
  __syncthreads();
  if (dp == 0) {
    float4 r = red[hq];
    float4 bi = ((const float4*)bin)[hq];
    float4 bc = ((const float4*)bctx)[hq];
    float4 o;
    o.x = a.x + r.x + bi.x + bc.x; o.y = a.y + r.y + bi.y + bc.y;
    o.z = a.z + r.z + bi.z + bc.z; o.w = a.w + r.w + bi.w + bc.w;
    ((float4*)qpb)[b * 128 + hq] = o;
  }
}

// ---------------- K2: fused ctx-GEMM + tanh + V-reduce -> att (pre-softmax) ----
// BK=32 single-buffered: LDS = 10240 (sA, 80B-stride rows) + 32768 (sB chunked)
// = 43008 B -> 3 blocks/CU (24 waves) vs previous 1 block (8 waves).
__global__ __launch_bounds__(512) void att_kernel(
    const float* __restrict__ ctxs, const void* __restrict__ mask,
    const int* __restrict__ mflag,
    const unsigned short* __restrict__ wpack, const float* __restrict__ qpb,
    const float* __restrict__ Vp, float* __restrict__ att_out) {
  __shared__ char lds[10240 + 32768];
  char* sA = lds;                        // [128 rows][80 B] (64 B data + 16 pad)
  char* sB = lds + 10240;                // 32 groups x (4 chunks x 16 rows x 16 B)
  float* att_red = (float*)lds;          // reused after final barrier

  const int tid  = threadIdx.x;
  const int wid  = tid >> 6;
  const int lane = tid & 63;
  const int ln15 = lane & 15;
  const int lk   = lane >> 4;
  const int wr   = wid >> 2;             // s-half
  const int wc   = wid & 3;              // h-quarter

  const int bx = blockIdx.x;
  const int b  = bx >> 4;
  const int s0 = (bx & 15) * 128;

  f32x4 acc[4][8];
  #pragma unroll
  for (int mi = 0; mi < 4; ++mi)
    #pragma unroll
    for (int ni = 0; ni < 8; ++ni)
      acc[mi][ni] = (f32x4){0.f, 0.f, 0.f, 0.f};

  const float* actx = ctxs + ((size_t)b * S_N + s0) * D_N;
  const int r0  = tid >> 3;              // rows r0 and r0+64
  const int c40 = tid & 7;               // float4 column within the 32-wide tile

  for (int t = 0; t < 16; ++t) {
    const int k0 = t * 32;
    __syncthreads();
    // stage A: 128 x 32 fp32 -> bf16 (packed cvt), padded-stride LDS
    {
      const float* g0 = actx + (size_t)r0 * D_N + k0 + c40 * 4;
      float4 v0 = *(const float4*)g0;
      float4 v1 = *(const float4*)(g0 + (size_t)64 * D_N);
      *(uint2*)(sA + r0 * 80 + c40 * 8) =
          make_uint2(pk2bf(v0.x, v0.y), pk2bf(v0.z, v0.w));
      *(uint2*)(sA + (r0 + 64) * 80 + c40 * 8) =
          make_uint2(pk2bf(v1.x, v1.y), pk2bf(v1.z, v1.w));
    }
    // stage B: 32 KB pre-chunked W tile, async global->LDS width 16
    {
      const char* wsrc = (const char*)wpack + t * 32768 + wid * 4096;
      char* ldst = sB + wid * 4096;
      #pragma unroll
      for (int c = 0; c < 4; ++c)
        __builtin_amdgcn_global_load_lds(
            (const __attribute__((address_space(1))) unsigned int*)(wsrc + c * 1024 + lane * 16),
            (__attribute__((address_space(3))) unsigned int*)(ldst + c * 1024 + lane * 16),
            16, 0, 0);
    }
    __syncthreads();
    // compute: one K=32 step, 4 mi x 8 ni MFMA
    bf16x8 af[4];
    #pragma unroll
    for (int mi = 0; mi < 4; ++mi) {
      int r = wr * 64 + mi * 16 + ln15;
      af[mi] = *(const bf16x8*)(sA + r * 80 + lk * 16);
    }
    #pragma unroll
    for (int ni = 0; ni < 8; ++ni) {
      bf16x8 bfr = *(const bf16x8*)(sB + (wc * 8 + ni) * 1024 + lk * 256 + ln15 * 16);
      #pragma unroll
      for (int mi = 0; mi < 4; ++mi)
        acc[mi][ni] = __builtin_amdgcn_mfma_f32_16x16x32_bf16(af[mi], bfr, acc[mi][ni], 0, 0, 0);
    }
  }

  // epilogue: att[s] = sum_h V[h] * tanh(qpb[b,h] + ctx[h][s])
  float qv[8], vv[8];
  #pragma unroll
  for (int ni = 0; ni < 8; ++ni) {
    int h = wc * 128 + ni * 16 + ln15;
    qv[ni] = qpb[b * H_N + h];
    vv[ni] = Vp[h];
  }
  float part[4][4];
  #pragma unroll
  for (int mi = 0; mi < 4; ++mi)
    #pragma unroll
    for (int j = 0; j < 4; ++j) {
      float s = 0.f;
      #pragma unroll
      for (int ni = 0; ni < 8; ++ni)
        s += vv[ni] * tanh_fast(qv[ni] + acc[mi][ni][j]);
      part[mi][j] = s;
    }
  #pragma unroll
  for (int mi = 0; mi < 4; ++mi)
    #pragma unroll
    for (int j = 0; j < 4; ++j) {
      float p = part[mi][j];
      p += __shfl_xor(p, 1, 64);
      p += __shfl_xor(p, 2, 64);
      p += __shfl_xor(p, 4, 64);
      p += __shfl_xor(p, 8, 64);
      part[mi][j] = p;
    }
  __syncthreads();
  if (ln15 == 0) {
    #pragma unroll
    for (int mi = 0; mi < 4; ++mi)
      #pragma unroll
      for (int j = 0; j < 4; ++j)
        att_red[wid * 64 + mi * 16 + lk * 4 + j] = part[mi][j];
  }
  __syncthreads();
  if (tid < 128) {
    int s = tid;
    int wrr = s >> 6, sl = s & 63;
    float a = att_red[(wrr * 4 + 0) * 64 + sl] + att_red[(wrr * 4 + 1) * 64 + sl]
            + att_red[(wrr * 4 + 2) * 64 + sl] + att_red[(wrr * 4 + 3) * 64 + sl];
    size_t idx = (size_t)b * S_N + s0 + s;
    int mk = (*mflag) ? ((const int*)mask)[idx]
                      : (int)((const unsigned char*)mask)[idx];
    att_out[idx] = mk ? -INFINITY : a;
  }
}

// ---------------- K3: masked softmax over S, in place ------------------------
__global__ __launch_bounds__(256) void softmax_kernel(float* __restrict__ score) {
  int b = blockIdx.x, tid = threadIdx.x;
  float* row = score + (size_t)b * S_N;
  float v[8];
  float m = -INFINITY;
  #pragma unroll
  for (int i = 0; i < 8; ++i) { v[i] = row[tid + i * 256]; m = fmaxf(m, v[i]); }
  #pragma unroll
  for (int d = 1; d < 64; d <<= 1) m = fmaxf(m, __shfl_xor(m, d, 64));
  __shared__ float redm[4], reds[4];
  int w = tid >> 6;
  if ((tid & 63) == 0) redm[w] = m;
  __syncthreads();
  m = fmaxf(fmaxf(redm[0], redm[1]), fmaxf(redm[2], redm[3]));
  float ssum = 0.f;
  #pragma unroll
  for (int i = 0; i < 8; ++i) { float e = __expf(v[i] - m); v[i] = e; ssum += e; }
  #pragma unroll
  for (int d = 1; d < 64; d <<= 1) ssum += __shfl_xor(ssum, d, 64);
  if ((tid & 63) == 0) reds[w] = ssum;
  __syncthreads();
  float inv = 1.0f / (reds[0] + reds[1] + reds[2] + reds[3]);
  #pragma unroll
  for (int i = 0; i < 8; ++i) row[tid + i * 256] = v[i] * inv;
}

// ---------------- K4: cbar[b,d] += sum_s score * contexts (float4/lane) -------
__global__ __launch_bounds__(256) void cbar_kernel(const float* __restrict__ ctxs,
    const float* __restrict__ score, float* __restrict__ cbar) {
  int bx = blockIdx.x;
  int b = bx >> 4, ch = bx & 15;         // s-chunk of 128
  int tid = threadIdx.x;
  __shared__ float sc[128];
  __shared__ float4 red[128];
  if (tid < 128) sc[tid] = score[(size_t)b * S_N + ch * 128 + tid];
  __syncthreads();
  int dq = tid & 127;                    // d = dq*4..dq*4+3
  int sp = tid >> 7;                     // s parity (wave-uniform)
  const float4* c4 = (const float4*)(ctxs + ((size_t)b * S_N + ch * 128) * D_N);
  float4 a = make_float4(0.f, 0.f, 0.f, 0.f);
  #pragma unroll 4
  for (int s = sp; s < 128; s += 2) {
    float w = sc[s];
    float4 c = c4[s * 128 + dq];
    a.x += w * c.x; a.y += w * c.y; a.z += w * c.z; a.w += w * c.w;
  }
  if (sp == 1) red[dq] = a;
  __syncthreads();
  if (sp == 0) {
    float4 r = red[dq];
    float* dst = cbar + b * D_N + dq * 4;
    atomicAdd(dst + 0, a.x + r.x);
    atomicAdd(dst + 1, a.y + r.y);
    atomicAdd(dst + 2, a.z + r.z);
    atomicAdd(dst + 3, a.w + r.w);
  }
}

// ---------------- K5: hidden[b,h] = W_ctx[h]·cbar[b] + b_ctx[h] (fp32) --------
__global__ __launch_bounds__(256) void hidden_kernel(const float* __restrict__ WcT,
    const float* __restrict__ bctx, const float* __restrict__ cbar,
    float* __restrict__ hid) {
  int b = blockIdx.x, tid = threadIdx.x;
  __shared__ float cb[D_N];
  __shared__ float4 red[128];
  cb[tid] = cbar[b * D_N + tid];
  cb[tid + 256] = cbar[b * D_N + tid + 256];
  __syncthreads();
  int hq = tid & 127;
  int dp = tid >> 7;
  const float4* wt = (const float4*)WcT;
  float4 a = make_float4(0.f, 0.f, 0.f, 0.f);
  #pragma unroll 8
  for (int d = dp; d < D_N; d += 2) {
    float xs = cb[d];
    float4 w = wt[d * 128 + hq];
    a.x += xs * w.x; a.y += xs * w.y; a.z += xs * w.z; a.w += xs * w.w;
  }
  if (dp == 1) red[hq] = a;
  __syncthreads();
  if (dp == 0) {
    float4 r = red[hq];
    float4 bc = ((const float4*)bctx)[hq];
    float4 o;
    o.x = a.x + r.x + bc.x; o.y = a.y + r.y + bc.y;
    o.z = a.z + r.z + bc.z; o.w = a.w + r.w + bc.w;
    ((float4*)hid)[b * 128 + hq] = o;
  }
}

extern "C" void kernel_launch(void* const* d_in, const int* in_sizes, int n_in,
                              void* d_out, int out_size, void* d_ws, size_t ws_size,
                              hipStream_t stream) {
  const float* inputs = (const float*)d_in[0];
  const float* ctxs   = (const float*)d_in[1];
  const void*  mask   = d_in[2];               // dtype detected on-device
  const float* Win    = (const float*)d_in[3];
  const float* bin    = (const float*)d_in[4];
  const float* Wc     = (const float*)d_in[5];
  const float* bctx   = (const float*)d_in[6];
  const float* Vp     = (const float*)d_in[7];

  float* hidden = (float*)d_out;               // [B,H]
  float* score  = (float*)d_out + B_N * H_N;   // [B,S]

  char* ws = (char*)d_ws;
  unsigned short* wpack = (unsigned short*)ws;       // 512 KB chunked bf16 W_ctx
  float* WinT = (float*)(ws + 512 * 1024);           // 1 MB  W_in^T  [D][H]
  float* WcT  = (float*)(ws + 1536 * 1024);          // 1 MB  W_ctx^T [D][H]
  float* qpb  = (float*)(ws + 2560 * 1024);          // 256 KB q + b_in + b_ctx
  float* cbar = (float*)(ws + 2816 * 1024);          // 256 KB weighted ctx sum
  int*   mflag = (int*)(ws + 3072 * 1024);           // 4 B

  hipMemsetAsync(cbar, 0, B_N * D_N * sizeof(float), stream);
  detect_mask_kernel<<<1, 64, 0, stream>>>((const unsigned int*)mask, mflag);
  packw_kernel<<<128, 256, 0, stream>>>(Wc, wpack);
  transpose_kernel<<<128, 256, 0, stream>>>(Win, Wc, WinT, WcT);
  qproj_kernel<<<B_N, 256, 0, stream>>>(inputs, WinT, bin, bctx, qpb);
  att_kernel<<<B_N * (S_N / 128), 512, 0, stream>>>(ctxs, mask, mflag, wpack, qpb, Vp, score);
  softmax_kernel<<<B_N, 256, 0, stream>>>(score);
  cbar_kernel<<<B_N * 16, 256, 0, stream>>>(ctxs, score, cbar);
  hidden_kernel<<<B_N, 256, 0, stream>>>(WcT, bctx, cbar, hidden);
}